// Round 4
// baseline (1086.704 us; speedup 1.0000x reference)
//
#include <hip/hip_runtime.h>
#include <hip/hip_bf16.h>

typedef __bf16 bf16x8 __attribute__((ext_vector_type(8)));
typedef float f32x4 __attribute__((ext_vector_type(4)));

typedef __attribute__((address_space(1))) const void GVoid;
typedef __attribute__((address_space(3))) void LVoid;

static __device__ __forceinline__ float b2f(unsigned short u) {
    union { float f; unsigned int i; } x; x.i = ((unsigned int)u) << 16; return x.f;
}
static __device__ __forceinline__ unsigned short f2b(float f) {
    union { float f; unsigned int u; } x; x.f = f;
    unsigned int r = x.u + 0x7FFFu + ((x.u >> 16) & 1u);
    return (unsigned short)(r >> 16);
}

// ---------------- prep ----------------
// blocks 0..1023  : W' row o = [Wh | Wl | Wh] (1536 wide) from Wq (o<512) / Wk
// blocks 1024..1535: Wvh row (o-1024) bf16
// block 1536      : biasA[1024] = bq|bk, biasV[512] = bv, relT[h][i][d] f32
__global__ __launch_bounds__(256) void k_prep(const float* __restrict__ Wq, const float* __restrict__ Wk,
                                              const float* __restrict__ Wv, const float* __restrict__ bq,
                                              const float* __restrict__ bk, const float* __restrict__ bv,
                                              const float* __restrict__ relw, unsigned short* __restrict__ Wp,
                                              unsigned short* __restrict__ Wvh, float* __restrict__ biasA,
                                              float* __restrict__ biasV, float* __restrict__ relT) {
    int o = blockIdx.x;
    int tid = threadIdx.x;
    if (o < 1024) {
        const float* src = (o < 512) ? (Wq + (long)o * 512) : (Wk + (long)(o - 512) * 512);
        for (int c = tid; c < 512; c += 256) {
            float f = src[c];
            unsigned short hi = f2b(f);
            unsigned short lo = f2b(f - b2f(hi));
            Wp[(long)o * 1536 + c] = hi;
            Wp[(long)o * 1536 + 512 + c] = lo;
            Wp[(long)o * 1536 + 1024 + c] = hi;
        }
    } else if (o < 1536) {
        const float* src = Wv + (long)(o - 1024) * 512;
        for (int c = tid; c < 512; c += 256) Wvh[(long)(o - 1024) * 512 + c] = f2b(src[c]);
    } else {
        for (int i = tid; i < 1024; i += 256) biasA[i] = (i < 512) ? bq[i] : bk[i - 512];
        for (int i = tid; i < 512; i += 256) biasV[i] = bv[i];
        // relT[h][i][d] = relw[h][d][i]
        for (int idx = tid; idx < 7168; idx += 256) {
            int h = idx / 1792, rem = idx % 1792, i = rem / 128, d = rem % 128;
            relT[idx] = relw[h * 1792 + d * 14 + i];
        }
    }
}

// ---------------- transpose: x[b][c][w] f32 -> At[(b,w)][0:512]=xh, [512:1024]=xlo ----------------
__global__ __launch_bounds__(256) void k_transpose(const float* __restrict__ x,
                                                   unsigned short* __restrict__ At, int b0) {
    __shared__ float xl[512 * 15];
    const float* xb = x + (long)(b0 + blockIdx.x) * 7168;
    const float4* xb4 = (const float4*)xb;
    int tid = threadIdx.x;
#pragma unroll
    for (int it = 0; it < 7; ++it) {
        int f = tid + it * 256;
        float4 v = xb4[f];
        float vals[4] = {v.x, v.y, v.z, v.w};
        int e = f * 4;
#pragma unroll
        for (int j = 0; j < 4; ++j) {
            int ee = e + j;
            int c = (ee * 9363) >> 17;
            int w = ee - c * 14;
            xl[c * 15 + w] = vals[j];
        }
    }
    __syncthreads();
    unsigned short* row0 = At + (long)blockIdx.x * 14336;
#pragma unroll
    for (int it = 0; it < 14; ++it) {
        int p = tid + it * 256;
        int w = p >> 8, cp = p & 255;
        int c0 = cp * 2;
        float v0 = xl[c0 * 15 + w], v1 = xl[(c0 + 1) * 15 + w];
        unsigned int h0 = f2b(v0), h1 = f2b(v1);
        unsigned int l0 = f2b(v0 - b2f((unsigned short)h0));
        unsigned int l1 = f2b(v1 - b2f((unsigned short)h1));
        *(unsigned int*)(row0 + (long)w * 1024 + c0) = h0 | (h1 << 16);
        *(unsigned int*)(row0 + (long)w * 1024 + 512 + c0) = l0 | (l1 << 16);
    }
}

// ---------------- GEMM-A: 256x256 tile, BK=32, 3-deep pipeline, counted vmcnt ----------------
// qk[(b,w)][n] = sum over K'=1536: A'=[xh|xh|xlo] (from At cols remapped), B'=Wp rows. f32 out + biasA.
__global__ __launch_bounds__(512, 2) void k_gemm256(const unsigned short* __restrict__ At,
                                                    const unsigned short* __restrict__ Wp,
                                                    const float* __restrict__ biasA,
                                                    float* __restrict__ qk, int Mtiles) {
    __shared__ unsigned short As[3][256 * 32];
    __shared__ unsigned short Bs[3][256 * 32];
    int nwg = Mtiles * 4;
    int p = blockIdx.x;
    int xcd = p & 7, o8 = p >> 3;
    int q8 = nwg >> 3, r8 = nwg & 7;
    int t = (xcd < r8 ? xcd * (q8 + 1) : r8 * (q8 + 1) + (xcd - r8) * q8) + o8;
    int mt = t >> 2, nt = t & 3;
    long m0 = (long)mt * 256;
    int n0 = nt * 256;
    int tid = threadIdx.x, lane = tid & 63, wv = tid >> 6;
    int wm = wv >> 2, wn = wv & 3;
    int srow = lane >> 2, su = lane & 3;  // stage: 16 rows x 4 16B-units per 1KB chunk

    f32x4 acc[8][4];
#pragma unroll
    for (int i = 0; i < 8; ++i)
#pragma unroll
        for (int j = 0; j < 4; ++j) acc[i][j] = (f32x4){0.f, 0.f, 0.f, 0.f};

#define STAGE(KT, BUF)                                                                     \
    {                                                                                      \
        int acol = (((KT) & 15) << 5) + (((KT) >> 5) << 9);                                \
        int bcol = (KT) << 5;                                                              \
        _Pragma("unroll") for (int ci = 0; ci < 2; ++ci) {                                 \
            int ch = wv * 2 + ci;                                                          \
            int row = ch * 16 + srow;                                                      \
            int un = (su + (row >> 2)) & 3;                                                \
            const unsigned short* sa = At + ((m0 + row) << 10) + acol + un * 8;            \
            const unsigned short* sb = Wp + (long)(n0 + row) * 1536 + bcol + un * 8;       \
            __builtin_amdgcn_global_load_lds((GVoid*)sa, (LVoid*)&As[BUF][ch * 512], 16, 0, 0); \
            __builtin_amdgcn_global_load_lds((GVoid*)sb, (LVoid*)&Bs[BUF][ch * 512], 16, 0, 0); \
        }                                                                                  \
    }

    STAGE(0, 0);
    STAGE(1, 1);
    asm volatile("s_waitcnt vmcnt(4)" ::: "memory");
    __builtin_amdgcn_s_barrier();
    __builtin_amdgcn_sched_barrier(0);

    int cur = 0;
    for (int kt = 0; kt < 48; ++kt) {
        int nxt2 = (cur == 0) ? 2 : cur - 1;  // (kt+2)%3
        if (kt + 2 < 48) STAGE(kt + 2, nxt2);

        bf16x8 af[8], bfr[4];
        const unsigned short* Ab = &As[cur][0];
        const unsigned short* Bb = &Bs[cur][0];
#pragma unroll
        for (int mf = 0; mf < 8; ++mf) {
            int row = wm * 128 + mf * 16 + (lane & 15);
            int uu = ((lane >> 4) - (row >> 2)) & 3;
            af[mf] = *(const bf16x8*)(Ab + row * 32 + uu * 8);
        }
#pragma unroll
        for (int nf = 0; nf < 4; ++nf) {
            int row = wn * 64 + nf * 16 + (lane & 15);
            int uu = ((lane >> 4) - (row >> 2)) & 3;
            bfr[nf] = *(const bf16x8*)(Bb + row * 32 + uu * 8);
        }
        __builtin_amdgcn_s_setprio(1);
#pragma unroll
        for (int mf = 0; mf < 8; ++mf)
#pragma unroll
            for (int nf = 0; nf < 4; ++nf)
                acc[mf][nf] = __builtin_amdgcn_mfma_f32_16x16x32_bf16(af[mf], bfr[nf], acc[mf][nf], 0, 0, 0);
        __builtin_amdgcn_s_setprio(0);

        if (kt + 2 < 48) asm volatile("s_waitcnt vmcnt(4)" ::: "memory");
        else             asm volatile("s_waitcnt vmcnt(0)" ::: "memory");
        __builtin_amdgcn_s_barrier();
        __builtin_amdgcn_sched_barrier(0);
        cur = (cur == 2) ? 0 : cur + 1;
    }
#undef STAGE

#pragma unroll
    for (int nf = 0; nf < 4; ++nf) {
        int n = n0 + wn * 64 + nf * 16 + (lane & 15);
        float bb = biasA[n];
#pragma unroll
        for (int mf = 0; mf < 8; ++mf) {
            long mg = m0 + wm * 128 + mf * 16 + ((lane >> 4) << 2);
#pragma unroll
            for (int r = 0; r < 4; ++r)
                qk[(mg + r) * 1024 + n] = acc[mf][nf][r] + bb;
        }
    }
}

// ---------------- GEMM-V: proven 128x128 kernel; A = xh half of At (stride 1024) ----------------
__global__ __launch_bounds__(256) void k_gemmv(const unsigned short* __restrict__ At,
                                               const unsigned short* __restrict__ Wvh,
                                               const float* __restrict__ biasV,
                                               unsigned short* __restrict__ vb, int Mtiles) {
    __shared__ unsigned short Ash[128 * 64];
    __shared__ unsigned short Bsh[128 * 64];
    int nwg = Mtiles * 4;
    int p = blockIdx.x;
    int xcd = p & 7, o8 = p >> 3;
    int q8 = nwg >> 3, r8 = nwg & 7;
    int t = (xcd < r8 ? xcd * (q8 + 1) : r8 * (q8 + 1) + (xcd - r8) * q8) + o8;
    int mt = t >> 2, nt = t & 3;
    long m0 = (long)mt * 128;
    int n0 = nt * 128;
    int tid = threadIdx.x, lane = tid & 63, wv = tid >> 6;
    int wr = wv >> 1, wc = wv & 1;
    int rrow = lane >> 3;
    int u = lane & 7;

    f32x4 acc[4][4];
#pragma unroll
    for (int i = 0; i < 4; ++i)
#pragma unroll
        for (int j = 0; j < 4; ++j) acc[i][j] = (f32x4){0.f, 0.f, 0.f, 0.f};

    for (int kt = 0; kt < 8; ++kt) {
        int kofs = kt * 64;
#pragma unroll
        for (int ti = 0; ti < 4; ++ti) {
            int chunk = wv * 4 + ti;
            int row = chunk * 8 + rrow;
            int colel = ((u ^ (row & 7)) << 3);
            const unsigned short* sa = At + ((m0 + row) << 10) + kofs + colel;
            const unsigned short* sb = Wvh + ((long)(n0 + row) << 9) + kofs + colel;
            __builtin_amdgcn_global_load_lds((GVoid*)sa, (LVoid*)(Ash + chunk * 512), 16, 0, 0);
            __builtin_amdgcn_global_load_lds((GVoid*)sb, (LVoid*)(Bsh + chunk * 512), 16, 0, 0);
        }
        asm volatile("s_waitcnt vmcnt(0)" ::: "memory");
        __syncthreads();
#pragma unroll
        for (int kk = 0; kk < 2; ++kk) {
            bf16x8 af[4], bfr[4];
            int kb = kk * 64 + ((lane >> 4) << 4);
#pragma unroll
            for (int mf = 0; mf < 4; ++mf) {
                int row = wr * 64 + mf * 16 + (lane & 15);
                af[mf] = *(const bf16x8*)((const char*)Ash + row * 128 + (kb ^ ((row & 7) << 4)));
            }
#pragma unroll
            for (int nf = 0; nf < 4; ++nf) {
                int row = wc * 64 + nf * 16 + (lane & 15);
                bfr[nf] = *(const bf16x8*)((const char*)Bsh + row * 128 + (kb ^ ((row & 7) << 4)));
            }
#pragma unroll
            for (int mf = 0; mf < 4; ++mf)
#pragma unroll
                for (int nf = 0; nf < 4; ++nf)
                    acc[mf][nf] = __builtin_amdgcn_mfma_f32_16x16x32_bf16(af[mf], bfr[nf], acc[mf][nf], 0, 0, 0);
        }
        __syncthreads();
    }
#pragma unroll
    for (int nf = 0; nf < 4; ++nf) {
        int n = n0 + wc * 64 + nf * 16 + (lane & 15);
        float bb = biasV[n];
#pragma unroll
        for (int mf = 0; mf < 4; ++mf) {
            long mg = m0 + wr * 64 + mf * 16 + ((lane >> 4) << 2);
#pragma unroll
            for (int r = 0; r < 4; ++r)
                vb[(mg + r) * 512 + n] = f2b(acc[mf][nf][r] + bb);
        }
    }
}

// ---------------- attention: one b per 512-thread block ----------------
// qk row (b,w): [0..511]=q, [512..1023]=k (f32). scores = q_i.k_j + rel_i.q_j
__global__ __launch_bounds__(512) void k_attn(const float* __restrict__ qkf,
                                              const unsigned short* __restrict__ vb,
                                              const float* __restrict__ relT,
                                              float* __restrict__ out, int b0) {
    __shared__ float qs[14 * 512];   // row w: 128 16B-units, unit ^ (w&7)
    __shared__ float ks[14 * 512];
    __shared__ float sl[56 * 16];
    int tid = threadIdx.x;
    long mb = (long)blockIdx.x * 14;
    const float4* qk4 = (const float4*)qkf;  // 256 units per row
#pragma unroll
    for (int it = 0; it < 7; ++it) {
        int idx = tid + it * 512;
        int w = idx >> 8, c4 = idx & 255;
        float4 v = qk4[(mb + w) * 256 + c4];
        int uu = c4 & 127;
        if (c4 < 128) *(float4*)&qs[w * 512 + ((uu ^ (w & 7)) << 2)] = v;
        else          *(float4*)&ks[w * 512 + ((uu ^ (w & 7)) << 2)] = v;
    }
    __syncthreads();
    if (tid < 196) {
        int h = tid / 49, r = tid - h * 49;
        int i0 = (r / 7) * 2, j0 = (r - (r / 7) * 7) * 2;
        const float4* rel4 = (const float4*)relT;
        float a00 = 0.f, a01 = 0.f, a10 = 0.f, a11 = 0.f;
#pragma unroll
        for (int d4 = 0; d4 < 32; ++d4) {
            int uu = h * 32 + d4;
            float4 qa = *(const float4*)&qs[i0 * 512 + ((uu ^ (i0 & 7)) << 2)];
            float4 qb = *(const float4*)&qs[(i0 + 1) * 512 + ((uu ^ ((i0 + 1) & 7)) << 2)];
            float4 ka = *(const float4*)&ks[j0 * 512 + ((uu ^ (j0 & 7)) << 2)];
            float4 kb = *(const float4*)&ks[(j0 + 1) * 512 + ((uu ^ ((j0 + 1) & 7)) << 2)];
            float4 qja = *(const float4*)&qs[j0 * 512 + ((uu ^ (j0 & 7)) << 2)];
            float4 qjb = *(const float4*)&qs[(j0 + 1) * 512 + ((uu ^ ((j0 + 1) & 7)) << 2)];
            float4 ra = rel4[(h * 14 + i0) * 32 + d4];
            float4 rb = rel4[(h * 14 + i0 + 1) * 32 + d4];
            a00 += qa.x * ka.x + qa.y * ka.y + qa.z * ka.z + qa.w * ka.w
                 + ra.x * qja.x + ra.y * qja.y + ra.z * qja.z + ra.w * qja.w;
            a01 += qa.x * kb.x + qa.y * kb.y + qa.z * kb.z + qa.w * kb.w
                 + ra.x * qjb.x + ra.y * qjb.y + ra.z * qjb.z + ra.w * qjb.w;
            a10 += qb.x * ka.x + qb.y * ka.y + qb.z * ka.z + qb.w * ka.w
                 + rb.x * qja.x + rb.y * qja.y + rb.z * qja.z + rb.w * qja.w;
            a11 += qb.x * kb.x + qb.y * kb.y + qb.z * kb.z + qb.w * kb.w
                 + rb.x * qjb.x + rb.y * qjb.y + rb.z * qjb.z + rb.w * qjb.w;
        }
        int base = (h * 14 + i0) * 16 + j0;
        sl[base] = a00;
        sl[base + 1] = a01;
        sl[base + 16] = a10;
        sl[base + 17] = a11;
    }
    __syncthreads();
    if (tid < 56) {
        float* row = &sl[tid * 16];
        float m = row[0];
#pragma unroll
        for (int j = 1; j < 14; ++j) m = fmaxf(m, row[j]);
        float ex[14]; float sum = 0.f;
#pragma unroll
        for (int j = 0; j < 14; ++j) { ex[j] = __expf(row[j] - m); sum += ex[j]; }
        float inv = 1.f / sum;
#pragma unroll
        for (int j = 0; j < 14; ++j) row[j] = ex[j] * inv;
    }
    __syncthreads();
    int c = tid, h = c >> 7;
    float vr[14];
#pragma unroll
    for (int j = 0; j < 14; ++j) vr[j] = b2f(vb[(mb + j) * 512 + c]);
    float* orow = out + (((long)(b0 + blockIdx.x) * 512 + c) * 14);
    float ob[14];
#pragma unroll
    for (int i = 0; i < 14; ++i) {
        const float* ar = &sl[(h * 14 + i) * 16];
        float a = 0.f;
#pragma unroll
        for (int j = 0; j < 14; ++j) a += vr[j] * ar[j];
        ob[i] = a;
    }
#pragma unroll
    for (int t2 = 0; t2 < 7; ++t2)
        *(float2*)(orow + t2 * 2) = make_float2(ob[2 * t2], ob[2 * t2 + 1]);
}

extern "C" void kernel_launch(void* const* d_in, const int* in_sizes, int n_in,
                              void* d_out, int out_size, void* d_ws, size_t ws_size,
                              hipStream_t stream) {
    const float* x    = (const float*)d_in[0];
    const float* Wq   = (const float*)d_in[1];
    const float* bq   = (const float*)d_in[2];
    const float* Wk   = (const float*)d_in[3];
    const float* bk   = (const float*)d_in[4];
    const float* Wv   = (const float*)d_in[5];
    const float* bv   = (const float*)d_in[6];
    const float* relw = (const float*)d_in[7];
    float* out = (float*)d_out;
    char* ws = (char*)d_ws;

    unsigned short* Wp    = (unsigned short*)ws;             // 1024*1536*2 = 3145728
    unsigned short* Wvh   = (unsigned short*)(ws + 3145728); // 512*512*2  = 524288
    float*          biasA = (float*)(ws + 3670016);          // 4096
    float*          biasV = (float*)(ws + 3674112);          // 2048
    float*          relT  = (float*)(ws + 3676160);          // 28672
    const long WS_DATA = 3706880;                            // 4KB-aligned

    // per-b: At 28672 + qk 57344 + vb 14336 = 100352 B
    long avail = (long)ws_size - WS_DATA;
    long nbmax = avail / 100352;
    long NBc = (nbmax / 128) * 128;
    if (NBc > 8192) NBc = 8192;
    if (NBc < 128) NBc = 128;

    unsigned short* At  = (unsigned short*)(ws + WS_DATA);
    float*          qkf = (float*)(At + NBc * 14336);
    unsigned short* vbw = (unsigned short*)(qkf + NBc * 14336);

    k_prep<<<1537, 256, 0, stream>>>(Wq, Wk, Wv, bq, bk, bv, relw, Wp, Wvh, biasA, biasV, relT);

    for (int b0 = 0; b0 < 8192; b0 += (int)NBc) {
        int nb = 8192 - b0; if (nb > NBc) nb = (int)NBc;
        int M = nb * 14;
        k_transpose<<<nb, 256, 0, stream>>>(x, At, b0);
        k_gemm256<<<(M / 256) * 4, 512, 0, stream>>>(At, Wp, biasA, qkf, M / 256);
        k_gemmv<<<(M / 128) * 4, 256, 0, stream>>>(At, Wvh, biasV, vbw, M / 128);
        k_attn<<<nb, 512, 0, stream>>>(qkf, vbw, relT, out, b0);
    }
}

// Round 5
// 757.719 us; speedup vs baseline: 1.4342x; 1.4342x over previous
//
#include <hip/hip_runtime.h>
#include <hip/hip_bf16.h>

typedef __bf16 bf16x8 __attribute__((ext_vector_type(8)));
typedef float f32x4 __attribute__((ext_vector_type(4)));
typedef int i32x4 __attribute__((ext_vector_type(4)));

typedef __attribute__((address_space(1))) const void GVoid;
typedef __attribute__((address_space(3))) void LVoid;

// quant scales (all exact in fp32): x ~ (Xh + Xl/250)/16 ; W ~ (Wh + Wl/250)/400 ; Relq ~ (Rh + Rl/250)/32
#define SX1 16.0f
#define SX1I 0.0625f
#define SX2 4000.0f
#define SW1 400.0f
#define SW1I 0.0025f
#define SW2 100000.0f
#define SR1 32.0f
#define SR1I 0.03125f
#define SR2 8000.0f
#define SC_QK 1.5625e-4f   /* 1/(16*400) */
#define SC_CP 1.953125e-3f /* 1/(16*32)  */
#define CORR 0.004f        /* 1/250 */

static __device__ __forceinline__ float b2f(unsigned short u) {
    union { float f; unsigned int i; } x; x.i = ((unsigned int)u) << 16; return x.f;
}
static __device__ __forceinline__ unsigned short f2b(float f) {
    union { float f; unsigned int u; } x; x.f = f;
    unsigned int r = x.u + 0x7FFFu + ((x.u >> 16) & 1u);
    return (unsigned short)(r >> 16);
}
static __device__ __forceinline__ int q8(float v, float s) {
    int i = __float2int_rn(v * s);
    return (i > 127) ? 127 : (i < -127 ? -127 : i);
}

// ---------------- prep ----------------
// blocks 0..1023   : Wq,Wk rows -> Wi8 rows [Wh(512) | Wl(512)]
// blocks 1024..1535: Wv rows -> Wvh bf16
// blocks 1536..1591: Relq[t][c] = sum_d rel[h,d,i]*Wq[h*128+d,c] -> Wi8 rows 1024..1079 + relbias
// block  1592      : biasA (bq|bk|skip-rel|zeros), biasV, zero Wi8 rows 1080..1151
__global__ __launch_bounds__(256) void k_prep(const float* __restrict__ Wq, const float* __restrict__ Wk,
                                              const float* __restrict__ Wv, const float* __restrict__ bq,
                                              const float* __restrict__ bk, const float* __restrict__ bv,
                                              const float* __restrict__ relw, char* __restrict__ Wi8,
                                              unsigned short* __restrict__ Wvh, float* __restrict__ biasA,
                                              float* __restrict__ biasV) {
    int o = blockIdx.x;
    int tid = threadIdx.x;
    if (o < 1024) {
        const float* src = (o < 512) ? (Wq + (long)o * 512) : (Wk + (long)(o - 512) * 512);
        char* row = Wi8 + (long)o * 1024;
        for (int c = tid; c < 512; c += 256) {
            float w = src[c];
            int wh = q8(w, SW1);
            float res = w - (float)wh * SW1I;
            int wl = q8(res, SW2);
            row[c] = (char)wh;
            row[512 + c] = (char)wl;
        }
    } else if (o < 1536) {
        const float* src = Wv + (long)(o - 1024) * 512;
        for (int c = tid; c < 512; c += 256) Wvh[(long)(o - 1024) * 512 + c] = f2b(src[c]);
    } else if (o < 1592) {
        int t = o - 1536, h = t / 14, i = t - h * 14;
        char* row = Wi8 + (long)(1024 + t) * 1024;
#pragma unroll
        for (int cc = 0; cc < 2; ++cc) {
            int c = tid + cc * 256;
            float acc = 0.f;
            for (int d = 0; d < 128; ++d)
                acc += relw[h * 1792 + d * 14 + i] * Wq[(long)(h * 128 + d) * 512 + c];
            int rh = q8(acc, SR1);
            float res = acc - (float)rh * SR1I;
            int rl = q8(res, SR2);
            row[c] = (char)rh;
            row[512 + c] = (char)rl;
        }
        if (tid == 0) {
            float acc = 0.f;
            for (int d = 0; d < 128; ++d) acc += relw[h * 1792 + d * 14 + i] * bq[h * 128 + d];
            biasA[1024 + t] = acc;
        }
    } else {
        for (int i = tid; i < 1152; i += 256) {
            if (i >= 1024 && i < 1080) continue;  // relbias written by Relq blocks
            biasA[i] = (i < 512) ? bq[i] : (i < 1024) ? bk[i - 512] : 0.f;
        }
        for (int i = tid; i < 512; i += 256) biasV[i] = bv[i];
        int* z = (int*)(Wi8 + 1080 * 1024);
        for (int idx = tid; idx < 72 * 256; idx += 256) z[idx] = 0;
    }
}

// ---------------- transpose: x[b][c][w] f32 -> Ai8[(b,w)][Xh(512)|Xl(512)] + Ah16[(b,w)][c] bf16 ----------------
__global__ __launch_bounds__(256) void k_transpose(const float* __restrict__ x,
                                                   char* __restrict__ Ai8,
                                                   unsigned short* __restrict__ Ah16, int b0) {
    __shared__ float xl[512 * 15];
    const float* xb = x + (long)(b0 + blockIdx.x) * 7168;
    const float4* xb4 = (const float4*)xb;
    int tid = threadIdx.x;
#pragma unroll
    for (int it = 0; it < 7; ++it) {
        int f = tid + it * 256;
        float4 v = xb4[f];
        float vals[4] = {v.x, v.y, v.z, v.w};
        int e = f * 4;
#pragma unroll
        for (int j = 0; j < 4; ++j) {
            int ee = e + j;
            int c = (ee * 9363) >> 17;
            int w = ee - c * 14;
            xl[c * 15 + w] = vals[j];
        }
    }
    __syncthreads();
    char* irow = Ai8 + (long)blockIdx.x * 14336;
    unsigned short* hrow = Ah16 + (long)blockIdx.x * 7168;
#pragma unroll
    for (int it = 0; it < 7; ++it) {
        int p = tid + it * 256;        // 1792 quads: w = p>>7, c0 = (p&127)*4
        int w = p >> 7, c0 = (p & 127) * 4;
        unsigned int hp = 0, lp = 0;
        unsigned short hb[4];
#pragma unroll
        for (int j = 0; j < 4; ++j) {
            float v = xl[(c0 + j) * 15 + w];
            int xh = q8(v, SX1);
            float res = v - (float)xh * SX1I;
            int xlo = q8(res, SX2);
            hp |= ((unsigned int)(xh & 255)) << (8 * j);
            lp |= ((unsigned int)(xlo & 255)) << (8 * j);
            hb[j] = f2b(v);
        }
        *(unsigned int*)(irow + (long)w * 1024 + c0) = hp;
        *(unsigned int*)(irow + (long)w * 1024 + 512 + c0) = lp;
        *(unsigned long long*)(hrow + (long)w * 512 + c0) =
            (unsigned long long)hb[0] | ((unsigned long long)hb[1] << 16) |
            ((unsigned long long)hb[2] << 32) | ((unsigned long long)hb[3] << 48);
    }
}

// ---------------- GEMM-A: split-i8, 128x128 tile, BK=64, N=1152, f32 out ----------------
// acc = (AhBh) + (AhBl + AlBh)/250 ; q = acc*scale + bias
__global__ __launch_bounds__(256) void k_gemmA(const char* __restrict__ Ai8,
                                               const char* __restrict__ Wi8,
                                               const float* __restrict__ biasA,
                                               float* __restrict__ qkf, int Mtiles) {
    __shared__ char Ahs[128 * 64];
    __shared__ char Als[128 * 64];
    __shared__ char Bhs[128 * 64];
    __shared__ char Bls[128 * 64];
    int nwg = Mtiles * 9;
    int p = blockIdx.x;
    int xcd = p & 7, o8 = p >> 3;
    int q8_ = nwg >> 3, r8 = nwg & 7;
    int t = (xcd < r8 ? xcd * (q8_ + 1) : r8 * (q8_ + 1) + (xcd - r8) * q8_) + o8;
    int mt = t / 9, nt = t - mt * 9;
    long m0 = (long)mt * 128;
    int n0 = nt * 128;
    int tid = threadIdx.x, lane = tid & 63, wv = tid >> 6;
    int wr = wv >> 1, wc = wv & 1;
    int rrow = lane >> 2;   // 16 rows per chunk
    int u = lane & 3;       // 4 16B units per 64B row

    i32x4 accM[4][4], accC[4][4];
#pragma unroll
    for (int i = 0; i < 4; ++i)
#pragma unroll
        for (int j = 0; j < 4; ++j) { accM[i][j] = (i32x4){0, 0, 0, 0}; accC[i][j] = (i32x4){0, 0, 0, 0}; }

    for (int kt = 0; kt < 8; ++kt) {
        int kof = kt * 64;
#pragma unroll
        for (int ci = 0; ci < 2; ++ci) {
            int ch = wv * 2 + ci;
            int row = ch * 16 + rrow;
            int gu = ((u ^ (row & 3)) << 4);
            const char* sa = Ai8 + ((m0 + row) << 10) + kof + gu;
            const char* sb = Wi8 + ((long)(n0 + row) << 10) + kof + gu;
            __builtin_amdgcn_global_load_lds((GVoid*)sa, (LVoid*)(Ahs + ch * 1024), 16, 0, 0);
            __builtin_amdgcn_global_load_lds((GVoid*)(sa + 512), (LVoid*)(Als + ch * 1024), 16, 0, 0);
            __builtin_amdgcn_global_load_lds((GVoid*)sb, (LVoid*)(Bhs + ch * 1024), 16, 0, 0);
            __builtin_amdgcn_global_load_lds((GVoid*)(sb + 512), (LVoid*)(Bls + ch * 1024), 16, 0, 0);
        }
        asm volatile("s_waitcnt vmcnt(0)" ::: "memory");
        __syncthreads();

        i32x4 ah[4], al[4], bh[4], bl[4];
#pragma unroll
        for (int mf = 0; mf < 4; ++mf) {
            int row = wr * 64 + mf * 16 + (lane & 15);
            int off = row * 64 + (((lane >> 4) ^ (row & 3)) << 4);
            ah[mf] = *(const i32x4*)(Ahs + off);
            al[mf] = *(const i32x4*)(Als + off);
        }
#pragma unroll
        for (int nf = 0; nf < 4; ++nf) {
            int row = wc * 64 + nf * 16 + (lane & 15);
            int off = row * 64 + (((lane >> 4) ^ (row & 3)) << 4);
            bh[nf] = *(const i32x4*)(Bhs + off);
            bl[nf] = *(const i32x4*)(Bls + off);
        }
#pragma unroll
        for (int mf = 0; mf < 4; ++mf)
#pragma unroll
            for (int nf = 0; nf < 4; ++nf) {
                accM[mf][nf] = __builtin_amdgcn_mfma_i32_16x16x64_i8(ah[mf], bh[nf], accM[mf][nf], 0, 0, 0);
                accC[mf][nf] = __builtin_amdgcn_mfma_i32_16x16x64_i8(ah[mf], bl[nf], accC[mf][nf], 0, 0, 0);
                accC[mf][nf] = __builtin_amdgcn_mfma_i32_16x16x64_i8(al[mf], bh[nf], accC[mf][nf], 0, 0, 0);
            }
        __syncthreads();
    }
#pragma unroll
    for (int nf = 0; nf < 4; ++nf) {
        int n = n0 + wc * 64 + nf * 16 + (lane & 15);
        float scale = (n < 1024) ? SC_QK : SC_CP;
        float bb = biasA[n];
#pragma unroll
        for (int mf = 0; mf < 4; ++mf) {
            long mg = m0 + wr * 64 + mf * 16 + ((lane >> 4) << 2);
#pragma unroll
            for (int r = 0; r < 4; ++r) {
                float val = ((float)accM[mf][nf][r] + CORR * (float)accC[mf][nf][r]) * scale + bb;
                if (n < 1080) qkf[(mg + r) * 1152 + n] = val;
            }
        }
    }
}

// ---------------- GEMM-V: proven 128x128 bf16 kernel; A = Ah16 (stride 512) ----------------
__global__ __launch_bounds__(256) void k_gemmv(const unsigned short* __restrict__ Ah16,
                                               const unsigned short* __restrict__ Wvh,
                                               const float* __restrict__ biasV,
                                               unsigned short* __restrict__ vb, int Mtiles) {
    __shared__ unsigned short Ash[128 * 64];
    __shared__ unsigned short Bsh[128 * 64];
    int nwg = Mtiles * 4;
    int p = blockIdx.x;
    int xcd = p & 7, o8 = p >> 3;
    int q8_ = nwg >> 3, r8 = nwg & 7;
    int t = (xcd < r8 ? xcd * (q8_ + 1) : r8 * (q8_ + 1) + (xcd - r8) * q8_) + o8;
    int mt = t >> 2, nt = t & 3;
    long m0 = (long)mt * 128;
    int n0 = nt * 128;
    int tid = threadIdx.x, lane = tid & 63, wv = tid >> 6;
    int wr = wv >> 1, wc = wv & 1;
    int rrow = lane >> 3;
    int u = lane & 7;

    f32x4 acc[4][4];
#pragma unroll
    for (int i = 0; i < 4; ++i)
#pragma unroll
        for (int j = 0; j < 4; ++j) acc[i][j] = (f32x4){0.f, 0.f, 0.f, 0.f};

    for (int kt = 0; kt < 8; ++kt) {
        int kofs = kt * 64;
#pragma unroll
        for (int ti = 0; ti < 4; ++ti) {
            int chunk = wv * 4 + ti;
            int row = chunk * 8 + rrow;
            int colel = ((u ^ (row & 7)) << 3);
            const unsigned short* sa = Ah16 + ((m0 + row) << 9) + kofs + colel;
            const unsigned short* sb = Wvh + ((long)(n0 + row) << 9) + kofs + colel;
            __builtin_amdgcn_global_load_lds((GVoid*)sa, (LVoid*)(Ash + chunk * 512), 16, 0, 0);
            __builtin_amdgcn_global_load_lds((GVoid*)sb, (LVoid*)(Bsh + chunk * 512), 16, 0, 0);
        }
        asm volatile("s_waitcnt vmcnt(0)" ::: "memory");
        __syncthreads();
#pragma unroll
        for (int kk = 0; kk < 2; ++kk) {
            bf16x8 af[4], bfr[4];
            int kb = kk * 64 + ((lane >> 4) << 4);
#pragma unroll
            for (int mf = 0; mf < 4; ++mf) {
                int row = wr * 64 + mf * 16 + (lane & 15);
                af[mf] = *(const bf16x8*)((const char*)Ash + row * 128 + (kb ^ ((row & 7) << 4)));
            }
#pragma unroll
            for (int nf = 0; nf < 4; ++nf) {
                int row = wc * 64 + nf * 16 + (lane & 15);
                bfr[nf] = *(const bf16x8*)((const char*)Bsh + row * 128 + (kb ^ ((row & 7) << 4)));
            }
#pragma unroll
            for (int mf = 0; mf < 4; ++mf)
#pragma unroll
                for (int nf = 0; nf < 4; ++nf)
                    acc[mf][nf] = __builtin_amdgcn_mfma_f32_16x16x32_bf16(af[mf], bfr[nf], acc[mf][nf], 0, 0, 0);
        }
        __syncthreads();
    }
#pragma unroll
    for (int nf = 0; nf < 4; ++nf) {
        int n = n0 + wc * 64 + nf * 16 + (lane & 15);
        float bb = biasV[n];
#pragma unroll
        for (int mf = 0; mf < 4; ++mf) {
            long mg = m0 + wr * 64 + mf * 16 + ((lane >> 4) << 2);
#pragma unroll
            for (int r = 0; r < 4; ++r)
                vb[(mg + r) * 512 + n] = f2b(acc[mf][nf][r] + bb);
        }
    }
}

// ---------------- attention: one b per 512-thread block (R3 proven) ----------------
// qkf row (b,w): [0..511]=q, [512..1023]=k, [1024..1079]=cp cols (h*14+i)
__global__ __launch_bounds__(512) void k_attn(const float* __restrict__ qkf,
                                              const unsigned short* __restrict__ vb,
                                              float* __restrict__ out, int b0) {
    __shared__ float qs[14 * 512];   // row w: 128 16B-units, unit idx ^ (w&7)
    __shared__ float ks[14 * 512];
    __shared__ float cps[56 * 16];   // [h*14+i][j]
    __shared__ float sl[56 * 16];
    __shared__ unsigned short vs[14 * 512];
    int tid = threadIdx.x;
    long mb = (long)blockIdx.x * 14;
    const float4* qk4 = (const float4*)qkf;  // 288 units per row
#pragma unroll
    for (int it = 0; it < 7; ++it) {
        int idx = tid + it * 512;
        int w = idx >> 8, c4 = idx & 255;
        float4 v = qk4[(mb + w) * 288 + c4];
        if (c4 < 128) *(float4*)&qs[w * 512 + ((c4 ^ (w & 7)) << 2)] = v;
        else {
            int uu = c4 - 128;
            *(float4*)&ks[w * 512 + ((uu ^ (w & 7)) << 2)] = v;
        }
    }
#pragma unroll
    for (int it = 0; it < 2; ++it) {
        int idx = tid + it * 512;
        if (idx < 784) {
            int w = idx / 56, tt = idx - w * 56;
            cps[tt * 16 + w] = qkf[(mb + w) * 1152 + 1024 + tt];
        }
    }
#pragma unroll
    for (int it = 0; it < 2; ++it) {
        int idx = tid + it * 512;
        if (idx < 896) {
            int w = idx >> 6, uu = idx & 63;
            *(uint4*)&vs[w * 512 + uu * 8] = *(const uint4*)&vb[(mb + w) * 512 + uu * 8];
        }
    }
    __syncthreads();
    if (tid < 196) {
        int h = tid / 49, r = tid - h * 49;
        int i0 = (r / 7) * 2, j0 = (r - (r / 7) * 7) * 2;
        float a00 = 0.f, a01 = 0.f, a10 = 0.f, a11 = 0.f;
#pragma unroll
        for (int d4 = 0; d4 < 32; ++d4) {
            int uu = h * 32 + d4;
            float4 qa = *(const float4*)&qs[i0 * 512 + ((uu ^ (i0 & 7)) << 2)];
            float4 qb = *(const float4*)&qs[(i0 + 1) * 512 + ((uu ^ ((i0 + 1) & 7)) << 2)];
            float4 ka = *(const float4*)&ks[j0 * 512 + ((uu ^ (j0 & 7)) << 2)];
            float4 kb = *(const float4*)&ks[(j0 + 1) * 512 + ((uu ^ ((j0 + 1) & 7)) << 2)];
            a00 += qa.x * ka.x + qa.y * ka.y + qa.z * ka.z + qa.w * ka.w;
            a01 += qa.x * kb.x + qa.y * kb.y + qa.z * kb.z + qa.w * kb.w;
            a10 += qb.x * ka.x + qb.y * ka.y + qb.z * ka.z + qb.w * ka.w;
            a11 += qb.x * kb.x + qb.y * kb.y + qb.z * kb.z + qb.w * kb.w;
        }
        int base = (h * 14 + i0) * 16 + j0;
        sl[base] = a00 + cps[base];
        sl[base + 1] = a01 + cps[base + 1];
        sl[base + 16] = a10 + cps[base + 16];
        sl[base + 17] = a11 + cps[base + 17];
    }
    __syncthreads();
    if (tid < 56) {
        float* row = &sl[tid * 16];
        float m = row[0];
#pragma unroll
        for (int j = 1; j < 14; ++j) m = fmaxf(m, row[j]);
        float ex[14]; float sum = 0.f;
#pragma unroll
        for (int j = 0; j < 14; ++j) { ex[j] = __expf(row[j] - m); sum += ex[j]; }
        float inv = 1.f / sum;
#pragma unroll
        for (int j = 0; j < 14; ++j) row[j] = ex[j] * inv;
    }
    __syncthreads();
    int c = tid, h = c >> 7;
    float vr[14];
#pragma unroll
    for (int j = 0; j < 14; ++j) vr[j] = b2f(vs[j * 512 + c]);
    float* orow = out + (((long)(b0 + blockIdx.x) * 512 + c) * 14);
    float ob[14];
#pragma unroll
    for (int i = 0; i < 14; ++i) {
        const float* ar = &sl[(h * 14 + i) * 16];
        float a = 0.f;
#pragma unroll
        for (int j = 0; j < 14; ++j) a += vr[j] * ar[j];
        ob[i] = a;
    }
#pragma unroll
    for (int t2 = 0; t2 < 7; ++t2)
        *(float2*)(orow + t2 * 2) = make_float2(ob[2 * t2], ob[2 * t2 + 1]);
}

extern "C" void kernel_launch(void* const* d_in, const int* in_sizes, int n_in,
                              void* d_out, int out_size, void* d_ws, size_t ws_size,
                              hipStream_t stream) {
    const float* x    = (const float*)d_in[0];
    const float* Wq   = (const float*)d_in[1];
    const float* bq   = (const float*)d_in[2];
    const float* Wk   = (const float*)d_in[3];
    const float* bk   = (const float*)d_in[4];
    const float* Wv   = (const float*)d_in[5];
    const float* bv   = (const float*)d_in[6];
    const float* relw = (const float*)d_in[7];
    float* out = (float*)d_out;
    char* ws = (char*)d_ws;

    char*           Wi8   = ws;                              // 1152*1024 = 1179648
    unsigned short* Wvh   = (unsigned short*)(ws + 1179648); // 524288
    float*          biasA = (float*)(ws + 1703936);          // 1152*4 = 4608
    float*          biasV = (float*)(ws + 1708544);          // 2048
    const long WS_DATA = 1712640;

    // per-b: Ai8 14336 + Ah16 14336 + qkf 64512 + vb 14336 = 107520 B
    long avail = (long)ws_size - WS_DATA;
    long nbmax = avail / 107520;
    long NBc = (nbmax / 128) * 128;
    if (NBc > 8192) NBc = 8192;
    if (NBc < 128) NBc = 128;

    char*           Ai8  = ws + WS_DATA;
    unsigned short* Ah16 = (unsigned short*)(Ai8 + NBc * 14336);
    float*          qkf  = (float*)(Ah16 + NBc * 7168);
    unsigned short* vbw  = (unsigned short*)(qkf + NBc * 16128);

    k_prep<<<1593, 256, 0, stream>>>(Wq, Wk, Wv, bq, bk, bv, relw, Wi8, Wvh, biasA, biasV);

    for (int b0 = 0; b0 < 8192; b0 += (int)NBc) {
        int nb = 8192 - b0; if (nb > NBc) nb = (int)NBc;
        int Mtiles = (nb * 14) / 128;
        k_transpose<<<nb, 256, 0, stream>>>(x, Ai8, Ah16, b0);
        k_gemmA<<<Mtiles * 9, 256, 0, stream>>>(Ai8, Wi8, biasA, qkf, Mtiles);
        k_gemmv<<<Mtiles * 4, 256, 0, stream>>>(Ah16, Wvh, biasV, vbw, Mtiles);
        k_attn<<<nb, 512, 0, stream>>>(qkf, vbw, out, b0);
    }
}